// Round 15
// baseline (513.264 us; speedup 1.0000x reference)
//
#include <hip/hip_runtime.h>

#define BN_EPS 1e-5f

typedef unsigned int uint32;

__device__ __forceinline__ void fma4(float4& a, float s, const float4& w) {
    a.x = fmaf(s, w.x, a.x); a.y = fmaf(s, w.y, a.y);
    a.z = fmaf(s, w.z, a.z); a.w = fmaf(s, w.w, a.w);
}

// bf16 helpers: packed pair in one u32 (lo = even col, hi = odd col)
__device__ __forceinline__ float blo(uint32 p) { return __uint_as_float(p << 16); }
__device__ __forceinline__ float bhi(uint32 p) { return __uint_as_float(p & 0xFFFF0000u); }
__device__ __forceinline__ uint32 f2bf1(float f) {
    uint32 u = __float_as_uint(f);
    return (u + 0x7FFFu + ((u >> 16) & 1u)) >> 16;   // RNE
}
__device__ __forceinline__ uint32 packbf(float a, float b) { return f2bf1(a) | (f2bf1(b) << 16); }

// ---------------- exclusive scan (CSR offsets) + dinv ----------------

__global__ __launch_bounds__(256) void k_scan1(const int* __restrict__ deg, int* __restrict__ off,
                                               int* __restrict__ bsum, float* __restrict__ dinv, int n) {
    __shared__ int sh[256];
    int i = blockIdx.x * 256 + threadIdx.x;
    int v = (i < n) ? deg[i] : 0;
    if (i < n) dinv[i] = rsqrtf((float)v + 1.0f);   // +1 = self-loop
    sh[threadIdx.x] = v;
    __syncthreads();
    #pragma unroll
    for (int d = 1; d < 256; d <<= 1) {
        int t = (threadIdx.x >= d) ? sh[threadIdx.x - d] : 0;
        __syncthreads();
        sh[threadIdx.x] += t;
        __syncthreads();
    }
    if (i < n) off[i] = sh[threadIdx.x] - v;
    if (threadIdx.x == 255) bsum[blockIdx.x] = sh[255];
}

__global__ __launch_bounds__(512) void k_scan2(int* bsum, int nb) {
    __shared__ int sh[512];
    int v = (threadIdx.x < nb) ? bsum[threadIdx.x] : 0;
    sh[threadIdx.x] = v;
    __syncthreads();
    #pragma unroll
    for (int d = 1; d < 512; d <<= 1) {
        int t = (threadIdx.x >= d) ? sh[threadIdx.x - d] : 0;
        __syncthreads();
        sh[threadIdx.x] += t;
        __syncthreads();
    }
    if (threadIdx.x < nb) bsum[threadIdx.x] = sh[threadIdx.x] - v;
}

__global__ __launch_bounds__(256) void k_scan3(int* __restrict__ off, const int* __restrict__ bsum,
                                               int* __restrict__ cnt, int n, int e) {
    int i = blockIdx.x * 256 + threadIdx.x;
    if (i < n) { off[i] += bsum[blockIdx.x]; cnt[i] = 0; }
    if (i == 0) off[n] = e;
}

// ---------------- fused: fc1 linear (even blocks) + degree count (odd blocks) ----------------

__global__ __launch_bounds__(256) void k_fc1_deg(const float* __restrict__ X, const float* __restrict__ W,
                                                 const float* __restrict__ bias, float* __restrict__ Y,
                                                 const int* __restrict__ dst, int* __restrict__ deg,
                                                 int n, int e, int nbLin) {
    constexpr int FIN = 128, FOUT = 64, KC = 64;
    constexpr int TX = FOUT / 4, TY = 256 / TX, RQ = 8, TILE_R = TY * RQ;  // 16,16,8,128
    __shared__ float Xs[TILE_R][KC + 4];
    __shared__ float Ws[KC][FOUT + 4];

    const int bid = blockIdx.x;
    const int twice = 2 * nbLin;
    bool isLin; int vid;
    if (bid < twice) { isLin = ((bid & 1) == 0); vid = bid >> 1; }
    else { isLin = false; vid = nbLin + (bid - twice); }

    if (!isLin) {
        const int ndeg = gridDim.x - nbLin;
        for (size_t i = (size_t)vid * 256 + threadIdx.x; i < (size_t)e; i += (size_t)ndeg * 256)
            atomicAdd(&deg[dst[i]], 1);
        return;
    }

    const int tx = threadIdx.x % TX;
    const int ty = threadIdx.x / TX;
    const float4 bb = *(const float4*)(bias + tx * 4);

    for (int r0 = vid * TILE_R; r0 < n; r0 += nbLin * TILE_R) {
        float4 acc[RQ];
        #pragma unroll
        for (int q = 0; q < RQ; ++q) acc[q] = bb;

        for (int kc = 0; kc < FIN; kc += KC) {
            __syncthreads();
            for (int idx = threadIdx.x; idx < TILE_R * (KC / 4); idx += 256) {
                int rr = idx / (KC / 4), k4 = idx % (KC / 4);
                int row = r0 + rr;
                float4 v = make_float4(0.f, 0.f, 0.f, 0.f);
                if (row < n) v = *(const float4*)(X + (size_t)row * FIN + kc + 4 * k4);
                *(float4*)(&Xs[rr][4 * k4]) = v;
            }
            for (int idx = threadIdx.x; idx < KC * (FOUT / 4); idx += 256) {
                int kk = idx / (FOUT / 4), c4 = idx % (FOUT / 4);
                *(float4*)(&Ws[kk][4 * c4]) = *(const float4*)(W + (size_t)(kc + kk) * FOUT + 4 * c4);
            }
            __syncthreads();

            #pragma unroll 4
            for (int k4 = 0; k4 < KC / 4; ++k4) {
                float4 w0 = *(const float4*)(&Ws[4*k4+0][tx*4]);
                float4 w1 = *(const float4*)(&Ws[4*k4+1][tx*4]);
                float4 w2 = *(const float4*)(&Ws[4*k4+2][tx*4]);
                float4 w3 = *(const float4*)(&Ws[4*k4+3][tx*4]);
                #pragma unroll
                for (int q = 0; q < RQ; ++q) {
                    float4 xv = *(const float4*)(&Xs[ty*RQ+q][4*k4]);
                    fma4(acc[q], xv.x, w0);
                    fma4(acc[q], xv.y, w1);
                    fma4(acc[q], xv.z, w2);
                    fma4(acc[q], xv.w, w3);
                }
            }
        }

        #pragma unroll
        for (int q = 0; q < RQ; ++q) {
            int row = r0 + ty * RQ + q;
            if (row < n) {
                float4 v = acc[q];
                v.x = fmaxf(v.x, 0.f); v.y = fmaxf(v.y, 0.f);
                v.z = fmaxf(v.z, 0.f); v.w = fmaxf(v.w, 0.f);
                *(float4*)(Y + (size_t)row * FOUT + tx * 4) = v;
            }
        }
    }
}

// ---------------- fused: conv0 linear (even blocks, CHUNKED bf16 out) + CSR fill (odd) ----------------
// chunk q (of 4) holds cols [16q,16q+16) as contiguous [n][32B] region.

__global__ __launch_bounds__(256) void k_conv0_fill(const float* __restrict__ X, const float* __restrict__ W,
                                                    uint2* __restrict__ Yb, const float* __restrict__ dinv,
                                                    const int* __restrict__ src, const int* __restrict__ dst,
                                                    const int* __restrict__ off, int* __restrict__ cnt,
                                                    int* __restrict__ esrc, int n, int e, int nbLin) {
    constexpr int FIN = 64, FOUT = 64, KC = 64;
    constexpr int TX = FOUT / 4, TY = 256 / TX, RQ = 8, TILE_R = TY * RQ;
    __shared__ float Xs[TILE_R][KC + 4];
    __shared__ float Ws[KC][FOUT + 4];

    const int bid = blockIdx.x;
    const int twice = 2 * nbLin;
    bool isLin; int vid;
    if (bid < twice) { isLin = ((bid & 1) == 0); vid = bid >> 1; }
    else { isLin = false; vid = nbLin + (bid - twice); }

    if (!isLin) {
        const int nfl = gridDim.x - nbLin;
        for (size_t i = (size_t)vid * 256 + threadIdx.x; i < (size_t)e; i += (size_t)nfl * 256) {
            int d = dst[i];
            int slot = off[d] + atomicAdd(&cnt[d], 1);
            esrc[slot] = src[i];
        }
        return;
    }

    const int tx = threadIdx.x % TX;
    const int ty = threadIdx.x / TX;
    const int cq = tx >> 2, cr = tx & 3;   // chunk, within-chunk uint2

    for (int r0 = vid * TILE_R; r0 < n; r0 += nbLin * TILE_R) {
        float4 acc[RQ];
        #pragma unroll
        for (int q = 0; q < RQ; ++q) acc[q] = make_float4(0.f, 0.f, 0.f, 0.f);

        __syncthreads();
        for (int idx = threadIdx.x; idx < TILE_R * (KC / 4); idx += 256) {
            int rr = idx / (KC / 4), k4 = idx % (KC / 4);
            int row = r0 + rr;
            float4 v = make_float4(0.f, 0.f, 0.f, 0.f);
            if (row < n) v = *(const float4*)(X + (size_t)row * FIN + 4 * k4);
            *(float4*)(&Xs[rr][4 * k4]) = v;
        }
        for (int idx = threadIdx.x; idx < KC * (FOUT / 4); idx += 256) {
            int kk = idx / (FOUT / 4), c4 = idx % (FOUT / 4);
            *(float4*)(&Ws[kk][4 * c4]) = *(const float4*)(W + (size_t)kk * FOUT + 4 * c4);
        }
        __syncthreads();

        #pragma unroll 4
        for (int k4 = 0; k4 < KC / 4; ++k4) {
            float4 w0 = *(const float4*)(&Ws[4*k4+0][tx*4]);
            float4 w1 = *(const float4*)(&Ws[4*k4+1][tx*4]);
            float4 w2 = *(const float4*)(&Ws[4*k4+2][tx*4]);
            float4 w3 = *(const float4*)(&Ws[4*k4+3][tx*4]);
            #pragma unroll
            for (int q = 0; q < RQ; ++q) {
                float4 xv = *(const float4*)(&Xs[ty*RQ+q][4*k4]);
                fma4(acc[q], xv.x, w0);
                fma4(acc[q], xv.y, w1);
                fma4(acc[q], xv.z, w2);
                fma4(acc[q], xv.w, w3);
            }
        }

        #pragma unroll
        for (int q = 0; q < RQ; ++q) {
            int row = r0 + ty * RQ + q;
            if (row < n) {
                float4 v = acc[q];
                float dv = dinv[row];
                v.x *= dv; v.y *= dv; v.z *= dv; v.w *= dv;
                uint2 pk;
                pk.x = packbf(v.x, v.y);
                pk.y = packbf(v.z, v.w);
                Yb[(size_t)cq * n * 4 + (size_t)row * 4 + cr] = pk;
            }
        }
    }
}

// ---------------- dense linear (template; conv1 chunked-bf16 out, conv2 row-major) ----------------

template<int FIN, int FOUT, bool RELU, bool BIAS, bool BNIN, bool DSCALE, bool OBF>
__global__ __launch_bounds__(256) void k_linear(const float* __restrict__ X, const float* __restrict__ W,
                                                const float* __restrict__ bias, void* __restrict__ Yv,
                                                const float* __restrict__ S, const float* __restrict__ bng,
                                                const float* __restrict__ bnb, const float* __restrict__ dinv,
                                                float inv_n, int n) {
    constexpr int KC = 64;
    constexpr int TX = FOUT / 4;
    constexpr int TY = 256 / TX;
    constexpr int RQ = (FOUT == 64) ? 8 : 2;
    constexpr int TILE_R = TY * RQ;
    __shared__ float Xs[TILE_R][KC + 4];
    __shared__ float Ws[KC][FOUT + 4];
    __shared__ float scs[BNIN ? FIN : 4], sfs[BNIN ? FIN : 4];

    const int tx = threadIdx.x % TX;
    const int ty = threadIdx.x / TX;

    if (BNIN) {
        for (int c = threadIdx.x; c < FIN; c += 256) {
            float mu = S[c] * inv_n;
            float var = S[FIN + c] * inv_n - mu * mu;
            float is = rsqrtf(var + BN_EPS) * bng[c];
            scs[c] = is;
            sfs[c] = bnb[c] - mu * is;
        }
        __syncthreads();
    }

    float4 bb = make_float4(0.f, 0.f, 0.f, 0.f);
    if (BIAS) bb = *(const float4*)(bias + tx * 4);

    for (int r0 = blockIdx.x * TILE_R; r0 < n; r0 += gridDim.x * TILE_R) {
        float4 acc[RQ];
        #pragma unroll
        for (int q = 0; q < RQ; ++q) acc[q] = bb;

        for (int kc = 0; kc < FIN; kc += KC) {
            __syncthreads();
            for (int idx = threadIdx.x; idx < TILE_R * (KC / 4); idx += 256) {
                int rr = idx / (KC / 4), k4 = idx % (KC / 4);
                int row = r0 + rr;
                float4 v = make_float4(0.f, 0.f, 0.f, 0.f);
                if (row < n) v = *(const float4*)(X + (size_t)row * FIN + kc + 4 * k4);
                if (BNIN) {
                    int c = kc + 4 * k4;
                    v.x = fmaxf(fmaf(v.x, scs[c+0], sfs[c+0]), 0.f);
                    v.y = fmaxf(fmaf(v.y, scs[c+1], sfs[c+1]), 0.f);
                    v.z = fmaxf(fmaf(v.z, scs[c+2], sfs[c+2]), 0.f);
                    v.w = fmaxf(fmaf(v.w, scs[c+3], sfs[c+3]), 0.f);
                }
                *(float4*)(&Xs[rr][4 * k4]) = v;
            }
            for (int idx = threadIdx.x; idx < KC * (FOUT / 4); idx += 256) {
                int kk = idx / (FOUT / 4), c4 = idx % (FOUT / 4);
                *(float4*)(&Ws[kk][4 * c4]) = *(const float4*)(W + (size_t)(kc + kk) * FOUT + 4 * c4);
            }
            __syncthreads();

            #pragma unroll 4
            for (int k4 = 0; k4 < KC / 4; ++k4) {
                float4 w0 = *(const float4*)(&Ws[4*k4+0][tx*4]);
                float4 w1 = *(const float4*)(&Ws[4*k4+1][tx*4]);
                float4 w2 = *(const float4*)(&Ws[4*k4+2][tx*4]);
                float4 w3 = *(const float4*)(&Ws[4*k4+3][tx*4]);
                #pragma unroll
                for (int q = 0; q < RQ; ++q) {
                    float4 xv = *(const float4*)(&Xs[ty*RQ+q][4*k4]);
                    fma4(acc[q], xv.x, w0);
                    fma4(acc[q], xv.y, w1);
                    fma4(acc[q], xv.z, w2);
                    fma4(acc[q], xv.w, w3);
                }
            }
        }

        #pragma unroll
        for (int q = 0; q < RQ; ++q) {
            int row = r0 + ty * RQ + q;
            if (row < n) {
                float4 v = acc[q];
                if (RELU) {
                    v.x = fmaxf(v.x, 0.f); v.y = fmaxf(v.y, 0.f);
                    v.z = fmaxf(v.z, 0.f); v.w = fmaxf(v.w, 0.f);
                }
                if (DSCALE) {
                    float dv = dinv[row];
                    v.x *= dv; v.y *= dv; v.z *= dv; v.w *= dv;
                }
                if (OBF) {
                    uint2 pk;
                    pk.x = packbf(v.x, v.y);
                    pk.y = packbf(v.z, v.w);
                    if (FOUT == 64) {
                        int cq = tx >> 2, cr = tx & 3;   // chunked layout for accum64
                        ((uint2*)Yv)[(size_t)cq * n * 4 + (size_t)row * 4 + cr] = pk;
                    } else {
                        ((uint2*)Yv)[(size_t)row * (FOUT / 4) + tx] = pk;
                    }
                } else {
                    *(float4*)((float*)Yv + (size_t)row * FOUT + tx * 4) = v;
                }
            }
        }
    }
}

// ---------------- GCN accumulate F=64: XCD-pinned chunks + DIRECT gather (no LDS ring) ----
// chunk p = [n][32B] (3.2 MB, L2-resident via bid&7 XCD pinning). Consumer lane =
// (edge-slot es 0..7, u32 cu 0..7); node PAIR per iteration -> 16 esrc + 16 chunk
// loads in flight; reduce = 3 shfl pairs per var; es==0 lanes write 16 cols/node.

__global__ __launch_bounds__(256) void k_accum64bf(const uint32* __restrict__ Tb, const int* __restrict__ esrc,
                                                   const int* __restrict__ off, const float* __restrict__ dinv,
                                                   const float* __restrict__ bias, float* __restrict__ Z,
                                                   float* __restrict__ S, int n, int e) {
    __shared__ float sA[4][16], sB[4][16];

    const int lane = threadIdx.x & 63;
    const int wid  = threadIdx.x >> 6;
    const int es   = lane >> 3;          // edge subset 0..7
    const int cu   = lane & 7;           // u32 index (cols 2cu, 2cu+1)

    const int q   = blockIdx.x & 7;      // XCD (round-robin heuristic)
    const int p   = q & 3;               // column chunk for this block
    const int grp = q >> 2;              // 0 or 1
    const int bpq = gridDim.x >> 3;      // blocks per XCD
    const int widx = (((blockIdx.x >> 3) + grp * bpq) << 2) + wid;
    const int NWc  = bpq * 8;            // waves per chunk

    const uint32* chunk = Tb + (size_t)p * n * 8;
    const float bc0 = bias[p * 16 + 2 * cu];
    const float bc1 = bias[p * 16 + 2 * cu + 1];
    float s1a = 0.f, s2a = 0.f, s1b = 0.f, s2b = 0.f;

    const int eS = (int)((long long)widx * e / NWc);
    const int eE = (int)((long long)(widx + 1) * e / NWc);

    int lo = 0, hi = n;
    while (lo < hi) { int mid = (lo + hi) >> 1; if (off[mid] < eS) lo = mid + 1; else hi = mid; }
    const int d0 = lo;
    int d1;
    if (widx == NWc - 1) d1 = n;
    else {
        lo = d0; hi = n;
        while (lo < hi) { int mid = (lo + hi) >> 1; if (off[mid] < eE) lo = mid + 1; else hi = mid; }
        d1 = lo;
    }

    for (int d = d0; d < d1; d += 2) {
        const int dA = d, dB = d + 1;
        const bool hasB = (dB < d1);
        const int oA0 = off[dA], oA1 = off[dA + 1];
        const int oB1 = hasB ? off[dB + 1] : oA1;

        float a0 = 0.f, a1 = 0.f, b0 = 0.f, b1 = 0.f;
        int iA = oA0 + es, iB = oA1 + es;
        while (iA < oA1 || iB < oB1) {
            if (iA < oA1) {
                int s = __builtin_nontemporal_load(esrc + iA);
                uint32 pw = chunk[(size_t)s * 8 + cu];
                a0 += blo(pw); a1 += bhi(pw);
            }
            if (iB < oB1) {
                int s = __builtin_nontemporal_load(esrc + iB);
                uint32 pw = chunk[(size_t)s * 8 + cu];
                b0 += blo(pw); b1 += bhi(pw);
            }
            iA += 8; iB += 8;
        }

        a0 += __shfl_xor(a0, 8);  a1 += __shfl_xor(a1, 8);
        a0 += __shfl_xor(a0, 16); a1 += __shfl_xor(a1, 16);
        a0 += __shfl_xor(a0, 32); a1 += __shfl_xor(a1, 32);
        b0 += __shfl_xor(b0, 8);  b1 += __shfl_xor(b1, 8);
        b0 += __shfl_xor(b0, 16); b1 += __shfl_xor(b1, 16);
        b0 += __shfl_xor(b0, 32); b1 += __shfl_xor(b1, 32);

        if (es == 0) {
            uint32 sw = chunk[(size_t)dA * 8 + cu];
            float dv = dinv[dA];
            float z0 = fmaf(a0 + blo(sw), dv, bc0);
            float z1 = fmaf(a1 + bhi(sw), dv, bc1);
            __builtin_nontemporal_store(z0, Z + (size_t)dA * 64 + p * 16 + 2 * cu);
            __builtin_nontemporal_store(z1, Z + (size_t)dA * 64 + p * 16 + 2 * cu + 1);
            s1a += z0; s2a += z0 * z0; s1b += z1; s2b += z1 * z1;
            if (hasB) {
                uint32 swB = chunk[(size_t)dB * 8 + cu];
                float dvB = dinv[dB];
                float y0 = fmaf(b0 + blo(swB), dvB, bc0);
                float y1 = fmaf(b1 + bhi(swB), dvB, bc1);
                __builtin_nontemporal_store(y0, Z + (size_t)dB * 64 + p * 16 + 2 * cu);
                __builtin_nontemporal_store(y1, Z + (size_t)dB * 64 + p * 16 + 2 * cu + 1);
                s1a += y0; s2a += y0 * y0; s1b += y1; s2b += y1 * y1;
            }
        }
    }

    if (wid == 0 && lane < 16) { sA[0][lane]=0.f; sA[1][lane]=0.f; sA[2][lane]=0.f; sA[3][lane]=0.f;
                                 sB[0][lane]=0.f; sB[1][lane]=0.f; sB[2][lane]=0.f; sB[3][lane]=0.f; }
    __syncthreads();
    if (es == 0) {
        sA[wid][2 * cu] = s1a; sA[wid][2 * cu + 1] = s1b;
        sB[wid][2 * cu] = s2a; sB[wid][2 * cu + 1] = s2b;
    }
    __syncthreads();
    if (threadIdx.x < 16) {
        float t1 = 0.f, t2 = 0.f;
        #pragma unroll
        for (int w = 0; w < 4; ++w) { t1 += sA[w][threadIdx.x]; t2 += sB[w][threadIdx.x]; }
        atomicAdd(&S[p * 16 + threadIdx.x], t1);
        atomicAdd(&S[64 + p * 16 + threadIdx.x], t2);
    }
}

// F=16: row = 4 uint2 (32 B); lp=lane&3, es=lane>>2 (16 slot groups), node pairs.

__global__ __launch_bounds__(256) void k_accum16bf(const uint2* __restrict__ Tb2, const int* __restrict__ esrc,
                                                   const int* __restrict__ off, const float* __restrict__ dinv,
                                                   const float* __restrict__ bias, float* __restrict__ Z,
                                                   float* __restrict__ S, int n) {
    const int lane = threadIdx.x & 63;
    const int wid  = threadIdx.x >> 6;
    const int lp   = lane & 3;
    const int es   = lane >> 2;
    const float4 bb = *(const float4*)(bias + 4 * lp);
    float st1[4] = {0.f,0.f,0.f,0.f}, st2[4] = {0.f,0.f,0.f,0.f};
    const uint2 z2 = make_uint2(0u, 0u);

    for (int dp = blockIdx.x * 4 + wid; 2 * dp < n; dp += gridDim.x * 4) {
        const int dA = 2 * dp, dB = 2 * dp + 1;
        const int oA0 = off[dA], oA1 = off[dA + 1];
        const int oB0 = oA1;
        const int oB1 = (dB < n) ? off[dB + 1] : oA1;

        float aA0=0.f, aA1=0.f, aA2=0.f, aA3=0.f;
        float aB0=0.f, aB1=0.f, aB2=0.f, aB3=0.f;
        int bA = oA0, bB = oB0;
        while (bA < oA1 || bB < oB1) {
            if (bA < oA1) {
                int i0 = bA + es;
                int s0 = (i0 < oA1) ? esrc[i0] : -1;
                uint2 p0 = (s0 >= 0) ? Tb2[(size_t)s0 * 4 + lp] : z2;
                aA0 += blo(p0.x); aA1 += bhi(p0.x); aA2 += blo(p0.y); aA3 += bhi(p0.y);
            }
            if (bB < oB1) {
                int i0 = bB + es;
                int s0 = (i0 < oB1) ? esrc[i0] : -1;
                uint2 p0 = (s0 >= 0) ? Tb2[(size_t)s0 * 4 + lp] : z2;
                aB0 += blo(p0.x); aB1 += bhi(p0.x); aB2 += blo(p0.y); aB3 += bhi(p0.y);
            }
            bA += 16; bB += 16;
        }

        #pragma unroll
        for (int sh = 4; sh <= 32; sh <<= 1) {
            aA0 += __shfl_xor(aA0, sh); aA1 += __shfl_xor(aA1, sh);
            aA2 += __shfl_xor(aA2, sh); aA3 += __shfl_xor(aA3, sh);
            aB0 += __shfl_xor(aB0, sh); aB1 += __shfl_xor(aB1, sh);
            aB2 += __shfl_xor(aB2, sh); aB3 += __shfl_xor(aB3, sh);
        }

        if (es == 0) {
            uint2 ps = Tb2[(size_t)dA * 4 + lp];
            float dv = dinv[dA];
            float4 zz;
            zz.x = fmaf(aA0 + blo(ps.x), dv, bb.x);
            zz.y = fmaf(aA1 + bhi(ps.x), dv, bb.y);
            zz.z = fmaf(aA2 + blo(ps.y), dv, bb.z);
            zz.w = fmaf(aA3 + bhi(ps.y), dv, bb.w);
            *(float4*)(Z + (size_t)dA * 16 + 4 * lp) = zz;
            st1[0] += zz.x; st2[0] += zz.x * zz.x;
            st1[1] += zz.y; st2[1] += zz.y * zz.y;
            st1[2] += zz.z; st2[2] += zz.z * zz.z;
            st1[3] += zz.w; st2[3] += zz.w * zz.w;
            if (dB < n) {
                uint2 pb = Tb2[(size_t)dB * 4 + lp];
                float dvB = dinv[dB];
                float4 zb;
                zb.x = fmaf(aB0 + blo(pb.x), dvB, bb.x);
                zb.y = fmaf(aB1 + bhi(pb.x), dvB, bb.y);
                zb.z = fmaf(aB2 + blo(pb.y), dvB, bb.z);
                zb.w = fmaf(aB3 + bhi(pb.y), dvB, bb.w);
                *(float4*)(Z + (size_t)dB * 16 + 4 * lp) = zb;
                st1[0] += zb.x; st2[0] += zb.x * zb.x;
                st1[1] += zb.y; st2[1] += zb.y * zb.y;
                st1[2] += zb.z; st2[2] += zb.z * zb.z;
                st1[3] += zb.w; st2[3] += zb.w * zb.w;
            }
        }
    }

    __shared__ float sh1[4][16], sh2[4][16];
    if (es == 0) {
        *(float4*)(&sh1[wid][4 * lp]) = make_float4(st1[0], st1[1], st1[2], st1[3]);
        *(float4*)(&sh2[wid][4 * lp]) = make_float4(st2[0], st2[1], st2[2], st2[3]);
    }
    __syncthreads();
    if (threadIdx.x < 16) {
        float t1 = 0.f, t2 = 0.f;
        #pragma unroll
        for (int w = 0; w < 4; ++w) { t1 += sh1[w][threadIdx.x]; t2 += sh2[w][threadIdx.x]; }
        atomicAdd(&S[threadIdx.x], t1);
        atomicAdd(&S[16 + threadIdx.x], t2);
    }
}

// ---------------- fc2 + log_softmax (fused BN+relu input) ----------------

__global__ __launch_bounds__(256) void k_fc2_lsm(const float* __restrict__ Hin, const float* __restrict__ W,
                                                 const float* __restrict__ bias, const float* __restrict__ S,
                                                 const float* __restrict__ bng, const float* __restrict__ bnb,
                                                 float inv_n, float* __restrict__ out, int n) {
    __shared__ float Ws[256];
    __shared__ float bs[16], sc[16], sf[16];
    Ws[threadIdx.x] = W[threadIdx.x];
    if (threadIdx.x < 16) {
        int c = threadIdx.x;
        bs[c] = bias[c];
        float mu = S[c] * inv_n;
        float var = S[16 + c] * inv_n - mu * mu;
        float is = rsqrtf(var + BN_EPS) * bng[c];
        sc[c] = is;
        sf[c] = bnb[c] - mu * is;
    }
    __syncthreads();
    for (int row = blockIdx.x * 256 + threadIdx.x; row < n; row += gridDim.x * 256) {
        float h[16];
        const float4* hp = (const float4*)(Hin + (size_t)row * 16);
        #pragma unroll
        for (int q = 0; q < 4; ++q) {
            float4 h4 = hp[q];
            h[q*4+0] = h4.x; h[q*4+1] = h4.y; h[q*4+2] = h4.z; h[q*4+3] = h4.w;
        }
        #pragma unroll
        for (int k = 0; k < 16; ++k) h[k] = fmaxf(fmaf(h[k], sc[k], sf[k]), 0.0f);
        float o[16];
        #pragma unroll
        for (int c = 0; c < 16; ++c) {
            float acc = bs[c];
            #pragma unroll
            for (int k = 0; k < 16; ++k) acc += h[k] * Ws[k * 16 + c];
            o[c] = acc;
        }
        float m = o[0];
        #pragma unroll
        for (int c = 1; c < 16; ++c) m = fmaxf(m, o[c]);
        float ssum = 0.f;
        #pragma unroll
        for (int c = 0; c < 16; ++c) ssum += expf(o[c] - m);
        float lse = m + logf(ssum);
        float4* op = (float4*)(out + (size_t)row * 16);
        #pragma unroll
        for (int q = 0; q < 4; ++q) {
            float4 w4;
            w4.x = o[q*4+0] - lse; w4.y = o[q*4+1] - lse;
            w4.z = o[q*4+2] - lse; w4.w = o[q*4+3] - lse;
            op[q] = w4;
        }
    }
}

// ---------------- launch ----------------

extern "C" void kernel_launch(void* const* d_in, const int* in_sizes, int n_in,
                              void* d_out, int out_size, void* d_ws, size_t ws_size,
                              hipStream_t stream) {
    const float* x      = (const float*)d_in[0];
    const int*   ei     = (const int*)d_in[1];
    const float* fc1_w  = (const float*)d_in[2];
    const float* fc1_b  = (const float*)d_in[3];
    const float* conv_w[3] = { (const float*)d_in[4],  (const float*)d_in[8],  (const float*)d_in[12] };
    const float* conv_b[3] = { (const float*)d_in[5],  (const float*)d_in[9],  (const float*)d_in[13] };
    const float* bn_g[3]   = { (const float*)d_in[6],  (const float*)d_in[10], (const float*)d_in[14] };
    const float* bn_b[3]   = { (const float*)d_in[7],  (const float*)d_in[11], (const float*)d_in[15] };
    const float* fc2_w  = (const float*)d_in[16];
    const float* fc2_b  = (const float*)d_in[17];

    const int n = in_sizes[0] / 128;
    const int e = in_sizes[1] / 2;
    const int* src = ei;
    const int* dst = ei + e;
    const float inv_n = 1.0f / (float)n;

    float*  A    = (float*)d_ws;            // n*64 f32
    float*  Bf   = A + (size_t)n * 64;      // n*64 region (bf16 uses half)
    uint32* Bb   = (uint32*)Bf;
    uint2*  Bb2  = (uint2*)Bf;
    float*  dinv = Bf + (size_t)n * 64;     // n
    int*    deg  = (int*)(dinv + n);        // n  (doubles as cnt)
    float*  stats = (float*)(deg + n);      // 3*128 (adjacent to deg: single memset)
    int*    off  = (int*)(stats + 384);     // n+1
    int*    esrc = off + n + 1;             // e
    int*    bsum = esrc + e;                // <=512

    const int gN  = (n + 255) / 256;
    const int gAcc = 2048;                  // must be multiple of 8 (XCD chunking)
    const int gLin = (n + 127) / 128;
    const int nbLin = gLin;
    const int gFused = 2048;

    float* st[3] = { stats, stats + 128, stats + 256 };

    // one memset covers deg + stats
    hipMemsetAsync(deg, 0, ((size_t)n + 384) * sizeof(int), stream);

    // fc1 + relu (even blocks) || degree count (odd blocks)
    k_fc1_deg<<<gFused, 256, 0, stream>>>(x, fc1_w, fc1_b, A, dst, deg, n, e, nbLin);

    k_scan1<<<gN, 256, 0, stream>>>(deg, off, bsum, dinv, n);
    k_scan2<<<1, 512, 0, stream>>>(bsum, gN);
    k_scan3<<<gN, 256, 0, stream>>>(off, bsum, deg /*cnt*/, n, e);

    // conv0 linear -> chunked bf16 (even blocks) || CSR fill (odd blocks)
    k_conv0_fill<<<gFused, 256, 0, stream>>>(A, conv_w[0], Bb2, dinv, src, dst, off, deg /*cnt*/, esrc, n, e, nbLin);
    k_accum64bf<<<gAcc, 256, 0, stream>>>(Bb, esrc, off, dinv, conv_b[0], A, st[0], n, e);

    // conv1 (chunked bf16 out)
    k_linear<64, 64, false, false, true, true, true><<<gLin, 256, 0, stream>>>(
        A, conv_w[1], nullptr, Bb, st[0], bn_g[0], bn_b[0], dinv, inv_n, n);
    k_accum64bf<<<gAcc, 256, 0, stream>>>(Bb, esrc, off, dinv, conv_b[1], A, st[1], n, e);

    // conv2 (64 -> 16, row-major bf16 out)
    k_linear<64, 16, false, false, true, true, true><<<gLin, 256, 0, stream>>>(
        A, conv_w[2], nullptr, Bb2, st[1], bn_g[1], bn_b[1], dinv, inv_n, n);
    k_accum16bf<<<gAcc, 256, 0, stream>>>(Bb2, esrc, off, dinv, conv_b[2], A, st[2], n);

    // fc2 + log_softmax (bn+relu fused on input) -> d_out
    k_fc2_lsm<<<gLin, 256, 0, stream>>>(A, fc2_w, fc2_b, st[2], bn_g[2], bn_b[2], inv_n, (float*)d_out, n);
}

// Round 16
// 403.343 us; speedup vs baseline: 1.2725x; 1.2725x over previous
//
#include <hip/hip_runtime.h>

#define BN_EPS 1e-5f

typedef unsigned int uint32;

__device__ __forceinline__ void fma4(float4& a, float s, const float4& w) {
    a.x = fmaf(s, w.x, a.x); a.y = fmaf(s, w.y, a.y);
    a.z = fmaf(s, w.z, a.z); a.w = fmaf(s, w.w, a.w);
}

// bf16 helpers: packed pair in one u32 (lo = even col, hi = odd col)
__device__ __forceinline__ float blo(uint32 p) { return __uint_as_float(p << 16); }
__device__ __forceinline__ float bhi(uint32 p) { return __uint_as_float(p & 0xFFFF0000u); }
__device__ __forceinline__ uint32 f2bf1(float f) {
    uint32 u = __float_as_uint(f);
    return (u + 0x7FFFu + ((u >> 16) & 1u)) >> 16;   // RNE
}
__device__ __forceinline__ uint32 packbf(float a, float b) { return f2bf1(a) | (f2bf1(b) << 16); }

// ---------------- exclusive scan (CSR offsets) + dinv ----------------

__global__ __launch_bounds__(256) void k_scan1(const int* __restrict__ deg, int* __restrict__ off,
                                               int* __restrict__ bsum, float* __restrict__ dinv, int n) {
    __shared__ int sh[256];
    int i = blockIdx.x * 256 + threadIdx.x;
    int v = (i < n) ? deg[i] : 0;
    if (i < n) dinv[i] = rsqrtf((float)v + 1.0f);   // +1 = self-loop
    sh[threadIdx.x] = v;
    __syncthreads();
    #pragma unroll
    for (int d = 1; d < 256; d <<= 1) {
        int t = (threadIdx.x >= d) ? sh[threadIdx.x - d] : 0;
        __syncthreads();
        sh[threadIdx.x] += t;
        __syncthreads();
    }
    if (i < n) off[i] = sh[threadIdx.x] - v;
    if (threadIdx.x == 255) bsum[blockIdx.x] = sh[255];
}

__global__ __launch_bounds__(512) void k_scan2(int* bsum, int nb) {
    __shared__ int sh[512];
    int v = (threadIdx.x < nb) ? bsum[threadIdx.x] : 0;
    sh[threadIdx.x] = v;
    __syncthreads();
    #pragma unroll
    for (int d = 1; d < 512; d <<= 1) {
        int t = (threadIdx.x >= d) ? sh[threadIdx.x - d] : 0;
        __syncthreads();
        sh[threadIdx.x] += t;
        __syncthreads();
    }
    if (threadIdx.x < nb) bsum[threadIdx.x] = sh[threadIdx.x] - v;
}

__global__ __launch_bounds__(256) void k_scan3(int* __restrict__ off, const int* __restrict__ bsum,
                                               int* __restrict__ cnt, int n, int e) {
    int i = blockIdx.x * 256 + threadIdx.x;
    if (i < n) { off[i] += bsum[blockIdx.x]; cnt[i] = 0; }
    if (i == 0) off[n] = e;
}

// ---------------- fused: fc1 linear (even blocks) + degree count (odd blocks) ----------------
// fc1: X[n,128] @ W[128,64] + b, relu, f32 out. deg: atomicAdd over dst.

__global__ __launch_bounds__(256) void k_fc1_deg(const float* __restrict__ X, const float* __restrict__ W,
                                                 const float* __restrict__ bias, float* __restrict__ Y,
                                                 const int* __restrict__ dst, int* __restrict__ deg,
                                                 int n, int e, int nbLin) {
    constexpr int FIN = 128, FOUT = 64, KC = 64;
    constexpr int TX = FOUT / 4, TY = 256 / TX, RQ = 8, TILE_R = TY * RQ;  // 16,16,8,128
    __shared__ float Xs[TILE_R][KC + 4];
    __shared__ float Ws[KC][FOUT + 4];

    const int bid = blockIdx.x;
    const int twice = 2 * nbLin;
    bool isLin; int vid;
    if (bid < twice) { isLin = ((bid & 1) == 0); vid = bid >> 1; }
    else { isLin = false; vid = nbLin + (bid - twice); }

    if (!isLin) {
        const int ndeg = gridDim.x - nbLin;
        for (size_t i = (size_t)vid * 256 + threadIdx.x; i < (size_t)e; i += (size_t)ndeg * 256)
            atomicAdd(&deg[dst[i]], 1);
        return;
    }

    const int tx = threadIdx.x % TX;
    const int ty = threadIdx.x / TX;
    const float4 bb = *(const float4*)(bias + tx * 4);

    for (int r0 = vid * TILE_R; r0 < n; r0 += nbLin * TILE_R) {
        float4 acc[RQ];
        #pragma unroll
        for (int q = 0; q < RQ; ++q) acc[q] = bb;

        for (int kc = 0; kc < FIN; kc += KC) {
            __syncthreads();
            for (int idx = threadIdx.x; idx < TILE_R * (KC / 4); idx += 256) {
                int rr = idx / (KC / 4), k4 = idx % (KC / 4);
                int row = r0 + rr;
                float4 v = make_float4(0.f, 0.f, 0.f, 0.f);
                if (row < n) v = *(const float4*)(X + (size_t)row * FIN + kc + 4 * k4);
                *(float4*)(&Xs[rr][4 * k4]) = v;
            }
            for (int idx = threadIdx.x; idx < KC * (FOUT / 4); idx += 256) {
                int kk = idx / (FOUT / 4), c4 = idx % (FOUT / 4);
                *(float4*)(&Ws[kk][4 * c4]) = *(const float4*)(W + (size_t)(kc + kk) * FOUT + 4 * c4);
            }
            __syncthreads();

            #pragma unroll 4
            for (int k4 = 0; k4 < KC / 4; ++k4) {
                float4 w0 = *(const float4*)(&Ws[4*k4+0][tx*4]);
                float4 w1 = *(const float4*)(&Ws[4*k4+1][tx*4]);
                float4 w2 = *(const float4*)(&Ws[4*k4+2][tx*4]);
                float4 w3 = *(const float4*)(&Ws[4*k4+3][tx*4]);
                #pragma unroll
                for (int q = 0; q < RQ; ++q) {
                    float4 xv = *(const float4*)(&Xs[ty*RQ+q][4*k4]);
                    fma4(acc[q], xv.x, w0);
                    fma4(acc[q], xv.y, w1);
                    fma4(acc[q], xv.z, w2);
                    fma4(acc[q], xv.w, w3);
                }
            }
        }

        #pragma unroll
        for (int q = 0; q < RQ; ++q) {
            int row = r0 + ty * RQ + q;
            if (row < n) {
                float4 v = acc[q];
                v.x = fmaxf(v.x, 0.f); v.y = fmaxf(v.y, 0.f);
                v.z = fmaxf(v.z, 0.f); v.w = fmaxf(v.w, 0.f);
                *(float4*)(Y + (size_t)row * FOUT + tx * 4) = v;
            }
        }
    }
}

// ---------------- fused: conv0 linear (even blocks) + CSR fill (odd blocks) ----------------
// conv0: Bb = bf16((A @ W0) * dinv[row]). fill: slot scatter of src by dst.

__global__ __launch_bounds__(256) void k_conv0_fill(const float* __restrict__ X, const float* __restrict__ W,
                                                    uint2* __restrict__ Yb, const float* __restrict__ dinv,
                                                    const int* __restrict__ src, const int* __restrict__ dst,
                                                    const int* __restrict__ off, int* __restrict__ cnt,
                                                    int* __restrict__ esrc, int n, int e, int nbLin) {
    constexpr int FIN = 64, FOUT = 64, KC = 64;
    constexpr int TX = FOUT / 4, TY = 256 / TX, RQ = 8, TILE_R = TY * RQ;  // 16,16,8,128
    __shared__ float Xs[TILE_R][KC + 4];
    __shared__ float Ws[KC][FOUT + 4];

    const int bid = blockIdx.x;
    const int twice = 2 * nbLin;
    bool isLin; int vid;
    if (bid < twice) { isLin = ((bid & 1) == 0); vid = bid >> 1; }
    else { isLin = false; vid = nbLin + (bid - twice); }

    if (!isLin) {
        const int nfl = gridDim.x - nbLin;
        for (size_t i = (size_t)vid * 256 + threadIdx.x; i < (size_t)e; i += (size_t)nfl * 256) {
            int d = dst[i];
            int slot = off[d] + atomicAdd(&cnt[d], 1);
            esrc[slot] = src[i];
        }
        return;
    }

    const int tx = threadIdx.x % TX;
    const int ty = threadIdx.x / TX;

    for (int r0 = vid * TILE_R; r0 < n; r0 += nbLin * TILE_R) {
        float4 acc[RQ];
        #pragma unroll
        for (int q = 0; q < RQ; ++q) acc[q] = make_float4(0.f, 0.f, 0.f, 0.f);

        __syncthreads();
        for (int idx = threadIdx.x; idx < TILE_R * (KC / 4); idx += 256) {
            int rr = idx / (KC / 4), k4 = idx % (KC / 4);
            int row = r0 + rr;
            float4 v = make_float4(0.f, 0.f, 0.f, 0.f);
            if (row < n) v = *(const float4*)(X + (size_t)row * FIN + 4 * k4);
            *(float4*)(&Xs[rr][4 * k4]) = v;
        }
        for (int idx = threadIdx.x; idx < KC * (FOUT / 4); idx += 256) {
            int kk = idx / (FOUT / 4), c4 = idx % (FOUT / 4);
            *(float4*)(&Ws[kk][4 * c4]) = *(const float4*)(W + (size_t)kk * FOUT + 4 * c4);
        }
        __syncthreads();

        #pragma unroll 4
        for (int k4 = 0; k4 < KC / 4; ++k4) {
            float4 w0 = *(const float4*)(&Ws[4*k4+0][tx*4]);
            float4 w1 = *(const float4*)(&Ws[4*k4+1][tx*4]);
            float4 w2 = *(const float4*)(&Ws[4*k4+2][tx*4]);
            float4 w3 = *(const float4*)(&Ws[4*k4+3][tx*4]);
            #pragma unroll
            for (int q = 0; q < RQ; ++q) {
                float4 xv = *(const float4*)(&Xs[ty*RQ+q][4*k4]);
                fma4(acc[q], xv.x, w0);
                fma4(acc[q], xv.y, w1);
                fma4(acc[q], xv.z, w2);
                fma4(acc[q], xv.w, w3);
            }
        }

        #pragma unroll
        for (int q = 0; q < RQ; ++q) {
            int row = r0 + ty * RQ + q;
            if (row < n) {
                float4 v = acc[q];
                float dv = dinv[row];
                v.x *= dv; v.y *= dv; v.z *= dv; v.w *= dv;
                uint2 pk;
                pk.x = packbf(v.x, v.y);
                pk.y = packbf(v.z, v.w);
                Yb[(size_t)row * (FOUT / 4) + tx] = pk;
            }
        }
    }
}

// ---------------- dense linear (template; conv1, conv2) ----------------

template<int FIN, int FOUT, bool RELU, bool BIAS, bool BNIN, bool DSCALE, bool OBF>
__global__ __launch_bounds__(256) void k_linear(const float* __restrict__ X, const float* __restrict__ W,
                                                const float* __restrict__ bias, void* __restrict__ Yv,
                                                const float* __restrict__ S, const float* __restrict__ bng,
                                                const float* __restrict__ bnb, const float* __restrict__ dinv,
                                                float inv_n, int n) {
    constexpr int KC = 64;
    constexpr int TX = FOUT / 4;
    constexpr int TY = 256 / TX;
    constexpr int RQ = (FOUT == 64) ? 8 : 2;
    constexpr int TILE_R = TY * RQ;
    constexpr int LDX = KC + 4;
    constexpr int LDW = FOUT + 4;
    __shared__ float Xs[TILE_R][LDX];
    __shared__ float Ws[KC][LDW];
    __shared__ float scs[BNIN ? FIN : 4], sfs[BNIN ? FIN : 4];

    const int tx = threadIdx.x % TX;
    const int ty = threadIdx.x / TX;

    if (BNIN) {
        for (int c = threadIdx.x; c < FIN; c += 256) {
            float mu = S[c] * inv_n;
            float var = S[FIN + c] * inv_n - mu * mu;
            float is = rsqrtf(var + BN_EPS) * bng[c];
            scs[c] = is;
            sfs[c] = bnb[c] - mu * is;
        }
        __syncthreads();
    }

    float4 bb = make_float4(0.f, 0.f, 0.f, 0.f);
    if (BIAS) bb = *(const float4*)(bias + tx * 4);

    for (int r0 = blockIdx.x * TILE_R; r0 < n; r0 += gridDim.x * TILE_R) {
        float4 acc[RQ];
        #pragma unroll
        for (int q = 0; q < RQ; ++q) acc[q] = bb;

        for (int kc = 0; kc < FIN; kc += KC) {
            __syncthreads();
            for (int idx = threadIdx.x; idx < TILE_R * (KC / 4); idx += 256) {
                int rr = idx / (KC / 4), k4 = idx % (KC / 4);
                int row = r0 + rr;
                float4 v = make_float4(0.f, 0.f, 0.f, 0.f);
                if (row < n) v = *(const float4*)(X + (size_t)row * FIN + kc + 4 * k4);
                if (BNIN) {
                    int c = kc + 4 * k4;
                    v.x = fmaxf(fmaf(v.x, scs[c+0], sfs[c+0]), 0.f);
                    v.y = fmaxf(fmaf(v.y, scs[c+1], sfs[c+1]), 0.f);
                    v.z = fmaxf(fmaf(v.z, scs[c+2], sfs[c+2]), 0.f);
                    v.w = fmaxf(fmaf(v.w, scs[c+3], sfs[c+3]), 0.f);
                }
                *(float4*)(&Xs[rr][4 * k4]) = v;
            }
            for (int idx = threadIdx.x; idx < KC * (FOUT / 4); idx += 256) {
                int kk = idx / (FOUT / 4), c4 = idx % (FOUT / 4);
                *(float4*)(&Ws[kk][4 * c4]) = *(const float4*)(W + (size_t)(kc + kk) * FOUT + 4 * c4);
            }
            __syncthreads();

            #pragma unroll 4
            for (int k4 = 0; k4 < KC / 4; ++k4) {
                float4 w0 = *(const float4*)(&Ws[4*k4+0][tx*4]);
                float4 w1 = *(const float4*)(&Ws[4*k4+1][tx*4]);
                float4 w2 = *(const float4*)(&Ws[4*k4+2][tx*4]);
                float4 w3 = *(const float4*)(&Ws[4*k4+3][tx*4]);
                #pragma unroll
                for (int q = 0; q < RQ; ++q) {
                    float4 xv = *(const float4*)(&Xs[ty*RQ+q][4*k4]);
                    fma4(acc[q], xv.x, w0);
                    fma4(acc[q], xv.y, w1);
                    fma4(acc[q], xv.z, w2);
                    fma4(acc[q], xv.w, w3);
                }
            }
        }

        #pragma unroll
        for (int q = 0; q < RQ; ++q) {
            int row = r0 + ty * RQ + q;
            if (row < n) {
                float4 v = acc[q];
                if (RELU) {
                    v.x = fmaxf(v.x, 0.f); v.y = fmaxf(v.y, 0.f);
                    v.z = fmaxf(v.z, 0.f); v.w = fmaxf(v.w, 0.f);
                }
                if (DSCALE) {
                    float dv = dinv[row];
                    v.x *= dv; v.y *= dv; v.z *= dv; v.w *= dv;
                }
                if (OBF) {
                    uint2 pk;
                    pk.x = packbf(v.x, v.y);
                    pk.y = packbf(v.z, v.w);
                    ((uint2*)Yv)[(size_t)row * (FOUT / 4) + tx] = pk;
                } else {
                    *(float4*)((float*)Yv + (size_t)row * FOUT + tx * 4) = v;
                }
            }
        }
    }
}

// ---------------- GCN accumulate F=64: edge-balanced stream + 3-deep ring pipeline ----------------

__global__ __launch_bounds__(256) void k_accum64bf(const uint32* __restrict__ Tb, const int* __restrict__ esrc,
                                                   const int* __restrict__ off, const float* __restrict__ dinv,
                                                   const float* __restrict__ bias, float* __restrict__ Z,
                                                   float* __restrict__ S, int n, int e) {
    __shared__ uint32 ring[4][2][256];   // [wave][slot][8 rows x 32 u32]
    __shared__ float sA[4][64], sB[4][64];

    const int lane = threadIdx.x & 63;
    const int wid  = threadIdx.x >> 6;
    const int rsub = lane >> 3;          // tile row 0..7
    const int csub = lane & 7;           // 16B chunk in row
    const int cidx = lane >> 1;          // u32 index of my bf16 column
    const int chal = lane & 1;           // low/high half
    const float bcol = bias[lane];

    float s1 = 0.f, s2 = 0.f;

    const int gw = blockIdx.x * 4 + wid;
    const int NW = gridDim.x * 4;
    const int eS = (int)((long long)gw * e / NW);
    const int eE = (int)((long long)(gw + 1) * e / NW);

    int lo = 0, hi = n;
    while (lo < hi) { int mid = (lo + hi) >> 1; if (off[mid] < eS) lo = mid + 1; else hi = mid; }
    const int d0 = lo;
    int d1;
    if (gw == NW - 1) d1 = n;
    else {
        lo = d0; hi = n;
        while (lo < hi) { int mid = (lo + hi) >> 1; if (off[mid] < eE) lo = mid + 1; else hi = mid; }
        d1 = lo;
    }

    if (d0 < d1) {
        const int e0 = off[d0];
        const int e1 = off[d1];
        const int nt = (e1 - e0 + 7) >> 3;

        uint32* slot0 = &ring[wid][0][0];
        uint32* slot1 = &ring[wid][1][0];

        int d = d0;
        int nxt = off[d + 1];
        uint32 selfp = Tb[(size_t)d * 32 + cidx];
        float  dv    = dinv[d];
        float  part  = 0.f;
        int    ec    = e0;

        auto tload = [&](int t) -> uint4 {
            int ei = min(e0 + t * 8 + rsub, e1 - 1);
            int s = esrc[ei];
            return ((const uint4*)Tb)[(size_t)s * 8 + csub];
        };

        uint4 B0, B1, B2;
        if (nt > 0) B0 = tload(0);
        if (nt > 1) B1 = tload(1);
        if (nt > 2) B2 = tload(2);

        for (int t = 0; t < nt; ++t) {
            uint32* sl = (t & 1) ? slot1 : slot0;
            uint4 cur = (t % 3 == 0) ? B0 : (t % 3 == 1) ? B1 : B2;
            *(uint4*)(sl + lane * 4) = cur;
            if (t + 3 < nt) {
                if (t % 3 == 0) B0 = tload(t + 3);
                else if (t % 3 == 1) B1 = tload(t + 3);
                else B2 = tload(t + 3);
            }
            int rend = min(8, e1 - (e0 + t * 8));
            for (int r = 0; r < rend; ++r) {
                while (ec == nxt) {
                    float sv = chal ? bhi(selfp) : blo(selfp);
                    float z = fmaf(part + sv, dv, bcol);
                    Z[(size_t)d * 64 + lane] = z;
                    s1 += z; s2 += z * z;
                    part = 0.f;
                    ++d;
                    nxt = off[d + 1];
                    selfp = Tb[(size_t)d * 32 + cidx];
                    dv = dinv[d];
                }
                uint32 p = sl[r * 32 + cidx];
                part += chal ? bhi(p) : blo(p);
                ++ec;
            }
        }
        while (d < d1) {
            float sv = chal ? bhi(selfp) : blo(selfp);
            float z = fmaf(part + sv, dv, bcol);
            Z[(size_t)d * 64 + lane] = z;
            s1 += z; s2 += z * z;
            part = 0.f;
            ++d;
            if (d < d1) {
                selfp = Tb[(size_t)d * 32 + cidx];
                dv = dinv[d];
            }
        }
    }

    sA[wid][lane] = s1;
    sB[wid][lane] = s2;
    __syncthreads();
    if (threadIdx.x < 64) {
        float t1 = 0.f, t2 = 0.f;
        #pragma unroll
        for (int w = 0; w < 4; ++w) { t1 += sA[w][threadIdx.x]; t2 += sB[w][threadIdx.x]; }
        atomicAdd(&S[threadIdx.x], t1);
        atomicAdd(&S[64 + threadIdx.x], t2);
    }
}

// F=16: row = 4 uint2 (32 B); lp=lane&3, es=lane>>2 (16 slot groups), node pairs.

__global__ __launch_bounds__(256) void k_accum16bf(const uint2* __restrict__ Tb2, const int* __restrict__ esrc,
                                                   const int* __restrict__ off, const float* __restrict__ dinv,
                                                   const float* __restrict__ bias, float* __restrict__ Z,
                                                   float* __restrict__ S, int n) {
    const int lane = threadIdx.x & 63;
    const int wid  = threadIdx.x >> 6;
    const int lp   = lane & 3;
    const int es   = lane >> 2;
    const float4 bb = *(const float4*)(bias + 4 * lp);
    float st1[4] = {0.f,0.f,0.f,0.f}, st2[4] = {0.f,0.f,0.f,0.f};
    const uint2 z2 = make_uint2(0u, 0u);

    for (int dp = blockIdx.x * 4 + wid; 2 * dp < n; dp += gridDim.x * 4) {
        const int dA = 2 * dp, dB = 2 * dp + 1;
        const int oA0 = off[dA], oA1 = off[dA + 1];
        const int oB0 = oA1;
        const int oB1 = (dB < n) ? off[dB + 1] : oA1;

        float aA0=0.f, aA1=0.f, aA2=0.f, aA3=0.f;
        float aB0=0.f, aB1=0.f, aB2=0.f, aB3=0.f;
        int bA = oA0, bB = oB0;
        while (bA < oA1 || bB < oB1) {
            if (bA < oA1) {
                int i0 = bA + es;
                int s0 = (i0 < oA1) ? esrc[i0] : -1;
                uint2 p0 = (s0 >= 0) ? Tb2[(size_t)s0 * 4 + lp] : z2;
                aA0 += blo(p0.x); aA1 += bhi(p0.x); aA2 += blo(p0.y); aA3 += bhi(p0.y);
            }
            if (bB < oB1) {
                int i0 = bB + es;
                int s0 = (i0 < oB1) ? esrc[i0] : -1;
                uint2 p0 = (s0 >= 0) ? Tb2[(size_t)s0 * 4 + lp] : z2;
                aB0 += blo(p0.x); aB1 += bhi(p0.x); aB2 += blo(p0.y); aB3 += bhi(p0.y);
            }
            bA += 16; bB += 16;
        }

        #pragma unroll
        for (int sh = 4; sh <= 32; sh <<= 1) {
            aA0 += __shfl_xor(aA0, sh); aA1 += __shfl_xor(aA1, sh);
            aA2 += __shfl_xor(aA2, sh); aA3 += __shfl_xor(aA3, sh);
            aB0 += __shfl_xor(aB0, sh); aB1 += __shfl_xor(aB1, sh);
            aB2 += __shfl_xor(aB2, sh); aB3 += __shfl_xor(aB3, sh);
        }

        if (es == 0) {
            uint2 ps = Tb2[(size_t)dA * 4 + lp];
            float dv = dinv[dA];
            float4 zz;
            zz.x = fmaf(aA0 + blo(ps.x), dv, bb.x);
            zz.y = fmaf(aA1 + bhi(ps.x), dv, bb.y);
            zz.z = fmaf(aA2 + blo(ps.y), dv, bb.z);
            zz.w = fmaf(aA3 + bhi(ps.y), dv, bb.w);
            *(float4*)(Z + (size_t)dA * 16 + 4 * lp) = zz;
            st1[0] += zz.x; st2[0] += zz.x * zz.x;
            st1[1] += zz.y; st2[1] += zz.y * zz.y;
            st1[2] += zz.z; st2[2] += zz.z * zz.z;
            st1[3] += zz.w; st2[3] += zz.w * zz.w;
            if (dB < n) {
                uint2 pb = Tb2[(size_t)dB * 4 + lp];
                float dvB = dinv[dB];
                float4 zb;
                zb.x = fmaf(aB0 + blo(pb.x), dvB, bb.x);
                zb.y = fmaf(aB1 + bhi(pb.x), dvB, bb.y);
                zb.z = fmaf(aB2 + blo(pb.y), dvB, bb.z);
                zb.w = fmaf(aB3 + bhi(pb.y), dvB, bb.w);
                *(float4*)(Z + (size_t)dB * 16 + 4 * lp) = zb;
                st1[0] += zb.x; st2[0] += zb.x * zb.x;
                st1[1] += zb.y; st2[1] += zb.y * zb.y;
                st1[2] += zb.z; st2[2] += zb.z * zb.z;
                st1[3] += zb.w; st2[3] += zb.w * zb.w;
            }
        }
    }

    __shared__ float sh1[4][16], sh2[4][16];
    if (es == 0) {
        *(float4*)(&sh1[wid][4 * lp]) = make_float4(st1[0], st1[1], st1[2], st1[3]);
        *(float4*)(&sh2[wid][4 * lp]) = make_float4(st2[0], st2[1], st2[2], st2[3]);
    }
    __syncthreads();
    if (threadIdx.x < 16) {
        float t1 = 0.f, t2 = 0.f;
        #pragma unroll
        for (int w = 0; w < 4; ++w) { t1 += sh1[w][threadIdx.x]; t2 += sh2[w][threadIdx.x]; }
        atomicAdd(&S[threadIdx.x], t1);
        atomicAdd(&S[16 + threadIdx.x], t2);
    }
}

// ---------------- fc2 + log_softmax (fused BN+relu input) ----------------

__global__ __launch_bounds__(256) void k_fc2_lsm(const float* __restrict__ Hin, const float* __restrict__ W,
                                                 const float* __restrict__ bias, const float* __restrict__ S,
                                                 const float* __restrict__ bng, const float* __restrict__ bnb,
                                                 float inv_n, float* __restrict__ out, int n) {
    __shared__ float Ws[256];
    __shared__ float bs[16], sc[16], sf[16];
    Ws[threadIdx.x] = W[threadIdx.x];
    if (threadIdx.x < 16) {
        int c = threadIdx.x;
        bs[c] = bias[c];
        float mu = S[c] * inv_n;
        float var = S[16 + c] * inv_n - mu * mu;
        float is = rsqrtf(var + BN_EPS) * bng[c];
        sc[c] = is;
        sf[c] = bnb[c] - mu * is;
    }
    __syncthreads();
    for (int row = blockIdx.x * 256 + threadIdx.x; row < n; row += gridDim.x * 256) {
        float h[16];
        const float4* hp = (const float4*)(Hin + (size_t)row * 16);
        #pragma unroll
        for (int q = 0; q < 4; ++q) {
            float4 h4 = hp[q];
            h[q*4+0] = h4.x; h[q*4+1] = h4.y; h[q*4+2] = h4.z; h[q*4+3] = h4.w;
        }
        #pragma unroll
        for (int k = 0; k < 16; ++k) h[k] = fmaxf(fmaf(h[k], sc[k], sf[k]), 0.0f);
        float o[16];
        #pragma unroll
        for (int c = 0; c < 16; ++c) {
            float acc = bs[c];
            #pragma unroll
            for (int k = 0; k < 16; ++k) acc += h[k] * Ws[k * 16 + c];
            o[c] = acc;
        }
        float m = o[0];
        #pragma unroll
        for (int c = 1; c < 16; ++c) m = fmaxf(m, o[c]);
        float ssum = 0.f;
        #pragma unroll
        for (int c = 0; c < 16; ++c) ssum += expf(o[c] - m);
        float lse = m + logf(ssum);
        float4* op = (float4*)(out + (size_t)row * 16);
        #pragma unroll
        for (int q = 0; q < 4; ++q) {
            float4 w4;
            w4.x = o[q*4+0] - lse; w4.y = o[q*4+1] - lse;
            w4.z = o[q*4+2] - lse; w4.w = o[q*4+3] - lse;
            op[q] = w4;
        }
    }
}

// ---------------- launch ----------------

extern "C" void kernel_launch(void* const* d_in, const int* in_sizes, int n_in,
                              void* d_out, int out_size, void* d_ws, size_t ws_size,
                              hipStream_t stream) {
    const float* x      = (const float*)d_in[0];
    const int*   ei     = (const int*)d_in[1];
    const float* fc1_w  = (const float*)d_in[2];
    const float* fc1_b  = (const float*)d_in[3];
    const float* conv_w[3] = { (const float*)d_in[4],  (const float*)d_in[8],  (const float*)d_in[12] };
    const float* conv_b[3] = { (const float*)d_in[5],  (const float*)d_in[9],  (const float*)d_in[13] };
    const float* bn_g[3]   = { (const float*)d_in[6],  (const float*)d_in[10], (const float*)d_in[14] };
    const float* bn_b[3]   = { (const float*)d_in[7],  (const float*)d_in[11], (const float*)d_in[15] };
    const float* fc2_w  = (const float*)d_in[16];
    const float* fc2_b  = (const float*)d_in[17];

    const int n = in_sizes[0] / 128;
    const int e = in_sizes[1] / 2;
    const int* src = ei;
    const int* dst = ei + e;
    const float inv_n = 1.0f / (float)n;

    float*  A    = (float*)d_ws;            // n*64 f32
    float*  Bf   = A + (size_t)n * 64;      // n*64 region (bf16 uses half)
    uint32* Bb   = (uint32*)Bf;
    uint2*  Bb2  = (uint2*)Bf;
    float*  dinv = Bf + (size_t)n * 64;     // n
    int*    deg  = (int*)(dinv + n);        // n  (doubles as cnt)
    float*  stats = (float*)(deg + n);      // 3*128 (adjacent to deg: single memset)
    int*    off  = (int*)(stats + 384);     // n+1
    int*    esrc = off + n + 1;             // e
    int*    bsum = esrc + e;                // <=512

    const int gN  = (n + 255) / 256;
    const int gAcc = 2048;
    const int gLin = (n + 127) / 128;       // TILE_R=128
    const int nbLin = gLin;
    const int gFused = 2048;                // even: linear, odd: edge work

    float* st[3] = { stats, stats + 128, stats + 256 };

    // one memset covers deg + stats
    hipMemsetAsync(deg, 0, ((size_t)n + 384) * sizeof(int), stream);

    // fc1 + relu (even blocks) || degree count (odd blocks)
    k_fc1_deg<<<gFused, 256, 0, stream>>>(x, fc1_w, fc1_b, A, dst, deg, n, e, nbLin);

    k_scan1<<<gN, 256, 0, stream>>>(deg, off, bsum, dinv, n);
    k_scan2<<<1, 512, 0, stream>>>(bsum, gN);
    k_scan3<<<gN, 256, 0, stream>>>(off, bsum, deg /*cnt*/, n, e);

    // conv0 linear -> bf16 (even blocks) || CSR fill (odd blocks)
    k_conv0_fill<<<gFused, 256, 0, stream>>>(A, conv_w[0], Bb2, dinv, src, dst, off, deg /*cnt*/, esrc, n, e, nbLin);
    k_accum64bf<<<gAcc, 256, 0, stream>>>(Bb, esrc, off, dinv, conv_b[0], A, st[0], n, e);

    // conv1
    k_linear<64, 64, false, false, true, true, true><<<gLin, 256, 0, stream>>>(
        A, conv_w[1], nullptr, Bb, st[0], bn_g[0], bn_b[0], dinv, inv_n, n);
    k_accum64bf<<<gAcc, 256, 0, stream>>>(Bb, esrc, off, dinv, conv_b[1], A, st[1], n, e);

    // conv2 (64 -> 16)
    k_linear<64, 16, false, false, true, true, true><<<gLin, 256, 0, stream>>>(
        A, conv_w[2], nullptr, Bb2, st[1], bn_g[1], bn_b[1], dinv, inv_n, n);
    k_accum16bf<<<gAcc, 256, 0, stream>>>(Bb2, esrc, off, dinv, conv_b[2], A, st[2], n);

    // fc2 + log_softmax (bn+relu fused on input) -> d_out
    k_fc2_lsm<<<gLin, 256, 0, stream>>>(A, fc2_w, fc2_b, st[2], bn_g[2], bn_b[2], inv_n, (float*)d_out, n);
}